// Round 12
// baseline (720.686 us; speedup 1.0000x reference)
//
#include <hip/hip_runtime.h>
#include <hip/hip_bf16.h>

// Relative-position causal attention, B=4 H=16 Q=K=1024 D=64 (fp32 in/out).
// d_out = [output (BH*Q*D) | p_attn (BH*Q*K)] fp32.
// Occupancy-first build: single-buffered 16KB LDS staging, 2 barriers/tile,
// 8 blocks/CU via __launch_bounds__(256,8). TLP hides HBM latency.
// K1 k_scores: content scores. K2 k_rel_pr: pass1 rel+exp+rowsum,
// pass2 normalize P in place + out = Pn@bigr_v (barrier-free direct loads).
// K3 k_pv: out += Pn @ V.

#define BH 64
#define SQ 1024
#define SK 1024
#define DH 64
#define SCALE 0.125f

typedef __attribute__((ext_vector_type(4))) float f32x4;
typedef __attribute__((ext_vector_type(8))) unsigned short ushort8;
typedef __attribute__((ext_vector_type(8))) __bf16 bf16x8;

static __device__ inline unsigned short f2bf(float x) {
    unsigned u = __float_as_uint(x);
    unsigned r = u + 0x7FFFu + ((u >> 16) & 1u);
    return (unsigned short)(r >> 16);
}
static __device__ inline float bf2f(unsigned short s) {
    return __uint_as_float(((unsigned)s) << 16);
}

struct Frag2 { bf16x8 h, l; };

// Load 8 fp32, scale, split into hi/lo bf16 fragments (hi+lo == scaled value).
static __device__ inline Frag2 load_split(const float* __restrict__ p, float scale) {
    float4 x0 = *reinterpret_cast<const float4*>(p);
    float4 x1 = *reinterpret_cast<const float4*>(p + 4);
    float v[8] = {x0.x, x0.y, x0.z, x0.w, x1.x, x1.y, x1.z, x1.w};
    ushort8 uh, ul;
#pragma unroll
    for (int j = 0; j < 8; ++j) {
        float s = v[j] * scale;
        unsigned short h = f2bf(s);
        float r = s - bf2f(h);
        uh[j] = h;
        ul[j] = f2bf(r);
    }
    Frag2 f;
    f.h = __builtin_bit_cast(bf16x8, uh);
    f.l = __builtin_bit_cast(bf16x8, ul);
    return f;
}

static __device__ inline bf16x8 pack_bf8(float4 x0, float4 x1) {
    float v[8] = {x0.x, x0.y, x0.z, x0.w, x1.x, x1.y, x1.z, x1.w};
    ushort8 u;
#pragma unroll
    for (int j = 0; j < 8; ++j) u[j] = f2bf(v[j]);
    return __builtin_bit_cast(bf16x8, u);
}

static __device__ inline bf16x8 load_bf8(const float* __restrict__ p) {
    float4 x0 = *reinterpret_cast<const float4*>(p);
    float4 x1 = *reinterpret_cast<const float4*>(p + 4);
    return pack_bf8(x0, x1);
}

static __device__ inline bf16x8 load_bf8_strided(const float* __restrict__ p, int stride) {
    ushort8 u;
#pragma unroll
    for (int j = 0; j < 8; ++j) u[j] = f2bf(p[(size_t)j * stride]);
    return __builtin_bit_cast(bf16x8, u);
}

#define MFMA(a, b, c) __builtin_amdgcn_mfma_f32_16x16x32_bf16((a), (b), (c), 0, 0, 0)

// async global -> LDS, 16B per lane; lds dest is wave-uniform base + lane*16
#define GLLD(g, s)                                                              \
    __builtin_amdgcn_global_load_lds(                                           \
        (const __attribute__((address_space(1))) void*)(g),                     \
        (__attribute__((address_space(3))) void*)(s), 16, 0, 0)

// stage a 64x64 fp32 tile (rows at src0 + row*DH) into buf; WAVE-PRIVATE rows:
// wave w stages rows [w*16, w*16+16) and later reads only those rows.
// source pre-swizzled (chunk ^= row&7) so linear LDS + swizzled reads match.
#define STAGE64(src0)                                                           \
    do {                                                                        \
        _Pragma("unroll")                                                       \
        for (int j_ = 0; j_ < 4; ++j_) {                                        \
            const int idx_ = w * 256 + j_ * 64 + l;                             \
            const int row_ = idx_ >> 4;                                         \
            const int g_ = (idx_ & 15) ^ (row_ & 7);                            \
            GLLD((src0) + (size_t)row_ * DH + g_ * 4,                           \
                 &buf[w * 256 + j_ * 64]);                                      \
        }                                                                       \
    } while (0)

// ---------------- K1: content scores Q@K^T * scale -> P (zeros above diag).
// Block = (q-tile 64, bh). Single-buffer staging, 2 barriers/tile, 8 blocks/CU.
__global__ __launch_bounds__(256, 8) void k_scores(const float* __restrict__ qp,
                                                   const float* __restrict__ kp,
                                                   float* __restrict__ P) {
    __shared__ float4 buf[1024];  // 16 KB
    const int qt = 15 - (int)blockIdx.x;  // big first
    const int bh = blockIdx.y;
    const int tid = threadIdx.x;
    const int w = tid >> 6, l = tid & 63;
    const int lm = l & 15, lg = l >> 4;
    const int q0 = qt * 64;

    Frag2 qh0[4], qh1[4];  // pre-scaled by SCALE
#pragma unroll
    for (int nt = 0; nt < 4; ++nt) {
        const float* qrow = qp + ((size_t)bh * SQ + q0 + nt * 16 + lm) * DH + lg * 8;
        qh0[nt] = load_split(qrow, SCALE);
        qh1[nt] = load_split(qrow + 32, SCALE);
    }
    const float* kb = kp + (size_t)bh * SK * DH;
    const int nt_ = qt + 1;

#pragma unroll 1
    for (int t = 0; t < nt_; ++t) {
        STAGE64(kb + (size_t)t * 64 * DH);
        __syncthreads();  // drains stage(t)
        const int R = w * 16 + lm;
        const int sw = R & 7;
        float4 f0 = buf[R * 16 + ((2 * lg) ^ sw)];
        float4 f1 = buf[R * 16 + ((2 * lg + 1) ^ sw)];
        float4 f2 = buf[R * 16 + ((8 + 2 * lg) ^ sw)];
        float4 f3 = buf[R * 16 + ((9 + 2 * lg) ^ sw)];
        bf16x8 alo = pack_bf8(f0, f1);
        bf16x8 ahi = pack_bf8(f2, f3);
        const int kq = t * 64 + w * 16 + lg * 4;
        const bool diag = (t == qt);
#pragma unroll
        for (int nt = 0; nt < 4; ++nt) {
            f32x4 acc = {0.f, 0.f, 0.f, 0.f};
            acc = MFMA(alo, qh0[nt].h, acc);
            acc = MFMA(alo, qh0[nt].l, acc);
            acc = MFMA(ahi, qh1[nt].h, acc);
            acc = MFMA(ahi, qh1[nt].l, acc);
            const int qe = q0 + nt * 16 + lm;
            float ov[4];
#pragma unroll
            for (int r = 0; r < 4; ++r)
                ov[r] = (!diag || (kq + r <= qe)) ? acc[r] : 0.f;
            float4 o;
            o.x = ov[0]; o.y = ov[1]; o.z = ov[2]; o.w = ov[3];
            *reinterpret_cast<float4*>(&P[((size_t)bh * SQ + qe) * SK + kq]) = o;
        }
        __syncthreads();  // all reads of buf done before next stage
    }
    // zero-fill tiles fully above the diagonal
    const float4 z = {0.f, 0.f, 0.f, 0.f};
#pragma unroll 1
    for (int t = nt_; t < 16; ++t) {
        const int kq = t * 64 + w * 16 + lg * 4;
#pragma unroll
        for (int nt = 0; nt < 4; ++nt) {
            const int qe = q0 + nt * 16 + lm;
            *reinterpret_cast<float4*>(&P[((size_t)bh * SQ + qe) * SK + kq]) = z;
        }
    }
}

// ---------------- K2: fused rel+exp+normalize+P@bigr_v. Block per q.
__global__ __launch_bounds__(256, 8) void k_rel_pr(const float* __restrict__ query,
                                                   const float* __restrict__ bigr_k,
                                                   const float* __restrict__ bigr_v,
                                                   float* __restrict__ P,
                                                   float* __restrict__ out) {
    __shared__ float4 buf[1024];  // 16 KB
    __shared__ float red[4][64];
    __shared__ float rsum[64];
    const int q = SQ - 1 - (int)blockIdx.x;  // big rows first
    const int KE = q + 1;
    const int nt_ = (KE + 63) >> 6;
    const int tid = threadIdx.x;
    const int w = tid >> 6, l = tid & 63;
    const int lm = l & 15, lg = l >> 4;

    // ---- pass 1: e = exp(content + rel), row sums ----
    Frag2 qh0[4], qh1[4];  // pre-scaled
    float* prow[4];
#pragma unroll
    for (int nt = 0; nt < 4; ++nt) {
        const int bh = nt * 16 + lm;
        const float* qrow = query + ((size_t)bh * SQ + q) * DH + lg * 8;
        qh0[nt] = load_split(qrow, SCALE);
        qh1[nt] = load_split(qrow + 32, SCALE);
        prow[nt] = P + ((size_t)bh * SQ + q) * SK;
    }
    const float* bk = bigr_k + (size_t)q * SK * DH;
    float lsum[4] = {0.f, 0.f, 0.f, 0.f};

#pragma unroll 1
    for (int t = 0; t < nt_; ++t) {
        STAGE64(bk + (size_t)t * 64 * DH);
        const int kq = t * 64 + w * 16 + lg * 4;
        float4 pc[4];
#pragma unroll
        for (int nt = 0; nt < 4; ++nt)
            pc[nt] = *reinterpret_cast<const float4*>(prow[nt] + kq);
        __syncthreads();  // drains stage(t) + pc
        const int R = w * 16 + lm;
        const int sw = R & 7;
        float4 f0 = buf[R * 16 + ((2 * lg) ^ sw)];
        float4 f1 = buf[R * 16 + ((2 * lg + 1) ^ sw)];
        float4 f2 = buf[R * 16 + ((8 + 2 * lg) ^ sw)];
        float4 f3 = buf[R * 16 + ((9 + 2 * lg) ^ sw)];
        bf16x8 alo = pack_bf8(f0, f1);
        bf16x8 ahi = pack_bf8(f2, f3);
#pragma unroll
        for (int nt = 0; nt < 4; ++nt) {
            f32x4 acc = {0.f, 0.f, 0.f, 0.f};
            acc = MFMA(alo, qh0[nt].h, acc);
            acc = MFMA(alo, qh0[nt].l, acc);
            acc = MFMA(ahi, qh1[nt].h, acc);
            acc = MFMA(ahi, qh1[nt].l, acc);
            const float4 c = pc[nt];
            float cv[4] = {c.x, c.y, c.z, c.w};
            float ov[4];
#pragma unroll
            for (int r = 0; r < 4; ++r) {
                float e = (kq + r < KE) ? __expf(cv[r] + acc[r]) : 0.f;
                ov[r] = e;
                lsum[nt] += e;
            }
            float4 o;
            o.x = ov[0]; o.y = ov[1]; o.z = ov[2]; o.w = ov[3];
            *reinterpret_cast<float4*>(prow[nt] + kq) = o;
        }
        __syncthreads();  // all reads of buf done before next stage
    }

    // ---- row-sum reduce -> recip in LDS ----
#pragma unroll
    for (int nt = 0; nt < 4; ++nt) {
        float v = lsum[nt];
        v += __shfl_xor(v, 16);
        v += __shfl_xor(v, 32);
        if (l < 16) red[w][nt * 16 + l] = v;
    }
    __syncthreads();
    if (tid < 64)
        rsum[tid] = 1.0f / (red[0][tid] + red[1][tid] + red[2][tid] + red[3][tid]);
    __syncthreads();

    // ---- pass 2: normalize P in place + out = Pn @ bigr_v[q]; no barriers ----
    const int bh0 = w * 16;
    const float* bv = bigr_v + (size_t)q * SK * DH;
    float* arow0 = P + ((size_t)(bh0 + lm) * SQ + q) * SK + lg * 8;
    const float nrm = rsum[bh0 + lm];
    f32x4 acc[4] = {{0.f,0.f,0.f,0.f},{0.f,0.f,0.f,0.f},{0.f,0.f,0.f,0.f},{0.f,0.f,0.f,0.f}};
#pragma unroll 2
    for (int k0 = 0; k0 < KE; k0 += 32) {
        float* arow = arow0 + k0;
        float4 x0 = *reinterpret_cast<const float4*>(arow);
        float4 x1 = *reinterpret_cast<const float4*>(arow + 4);
        float4 y0 = {x0.x * nrm, x0.y * nrm, x0.z * nrm, x0.w * nrm};
        float4 y1 = {x1.x * nrm, x1.y * nrm, x1.z * nrm, x1.w * nrm};
        *reinterpret_cast<float4*>(arow) = y0;       // final normalized p_attn
        *reinterpret_cast<float4*>(arow + 4) = y1;
        bf16x8 a = pack_bf8(y0, y1);
#pragma unroll
        for (int nt = 0; nt < 4; ++nt) {
            const float* bcol = bv + (size_t)(k0 + lg * 8) * DH + nt * 16 + lm;
            bf16x8 b = load_bf8_strided(bcol, DH);
            acc[nt] = MFMA(a, b, acc[nt]);
        }
    }
#pragma unroll
    for (int nt = 0; nt < 4; ++nt)
#pragma unroll
        for (int r = 0; r < 4; ++r)
            out[((size_t)(bh0 + lg * 4 + r) * SQ + q) * DH + nt * 16 + lm] = acc[nt][r];
}

// ---------------- K3: out += Pn @ V (per bh, q-tiles of 64)
__global__ __launch_bounds__(256) void k_pv(const float* __restrict__ P,
                                            const float* __restrict__ V,
                                            float* __restrict__ out) {
    const int qt = 15 - (int)blockIdx.x;  // big tiles first
    const int bh = blockIdx.y;
    const int tid = threadIdx.x;
    const int w = tid >> 6, l = tid & 63;
    const int lm = l & 15, lg = l >> 4;
    const int q0 = qt * 64 + w * 16;

    f32x4 acc[4] = {{0.f,0.f,0.f,0.f},{0.f,0.f,0.f,0.f},{0.f,0.f,0.f,0.f},{0.f,0.f,0.f,0.f}};
    const int kend = q0 + 16;
    for (int k0 = 0; k0 < kend; k0 += 32) {
        const float* arow = P + ((size_t)bh * SQ + q0 + lm) * SK + k0 + lg * 8;
        bf16x8 a = load_bf8(arow);
#pragma unroll
        for (int nt = 0; nt < 4; ++nt) {
            const float* bcol = V + ((size_t)bh * SK + k0 + lg * 8) * DH + nt * 16 + lm;
            bf16x8 b = load_bf8_strided(bcol, DH);
            acc[nt] = MFMA(a, b, acc[nt]);
        }
    }
#pragma unroll
    for (int nt = 0; nt < 4; ++nt)
#pragma unroll
        for (int r = 0; r < 4; ++r)
            out[((size_t)bh * SQ + q0 + lg * 4 + r) * DH + nt * 16 + lm] += acc[nt][r];
}

extern "C" void kernel_launch(void* const* d_in, const int* in_sizes, int n_in,
                              void* d_out, int out_size, void* d_ws, size_t ws_size,
                              hipStream_t stream) {
    const float* query  = (const float*)d_in[0];
    const float* key    = (const float*)d_in[1];
    const float* value  = (const float*)d_in[2];
    const float* bigr_k = (const float*)d_in[3];
    const float* bigr_v = (const float*)d_in[4];
    float* out = (float*)d_out;                       // BH*SQ*DH
    float* P   = out + (size_t)BH * SQ * DH;          // BH*SQ*SK

    k_scores<<<dim3(16, BH), 256, 0, stream>>>(query, key, P);
    k_rel_pr<<<dim3(SQ), 256, 0, stream>>>(query, bigr_k, bigr_v, P, out);
    k_pv<<<dim3(16, BH), 256, 0, stream>>>(P, value, out);
}

// Round 13
// 590.335 us; speedup vs baseline: 1.2208x; 1.2208x over previous
//
#include <hip/hip_runtime.h>
#include <hip/hip_bf16.h>

// Relative-position causal attention, B=4 H=16 Q=K=1024 D=64 (fp32 in/out).
// d_out = [output (BH*Q*D) | p_attn (BH*Q*K)] fp32.
// R9 base + pass1 pc-prefetch pipeline (uniform vmcnt(8), 2-deep).
// K1 k_scores: content scores, per-wave glld pipeline (counted vmcnt).
// K2 k_rel_pr: pass1 rel+exp (stage+pc both 1 tile ahead) + row sum;
//              pass2 normalize P in place + out = Pn@bigr_v (direct strided B).
// K3 k_pv: out += Pn @ V.

#define BH 64
#define SQ 1024
#define SK 1024
#define DH 64
#define SCALE 0.125f

typedef __attribute__((ext_vector_type(4))) float f32x4;
typedef __attribute__((ext_vector_type(8))) unsigned short ushort8;
typedef __attribute__((ext_vector_type(8))) __bf16 bf16x8;

static __device__ inline unsigned short f2bf(float x) {
    unsigned u = __float_as_uint(x);
    unsigned r = u + 0x7FFFu + ((u >> 16) & 1u);
    return (unsigned short)(r >> 16);
}
static __device__ inline float bf2f(unsigned short s) {
    return __uint_as_float(((unsigned)s) << 16);
}

struct Frag2 { bf16x8 h, l; };

// Load 8 fp32, scale, split into hi/lo bf16 fragments (hi+lo == scaled value).
static __device__ inline Frag2 load_split(const float* __restrict__ p, float scale) {
    float4 x0 = *reinterpret_cast<const float4*>(p);
    float4 x1 = *reinterpret_cast<const float4*>(p + 4);
    float v[8] = {x0.x, x0.y, x0.z, x0.w, x1.x, x1.y, x1.z, x1.w};
    ushort8 uh, ul;
#pragma unroll
    for (int j = 0; j < 8; ++j) {
        float s = v[j] * scale;
        unsigned short h = f2bf(s);
        float r = s - bf2f(h);
        uh[j] = h;
        ul[j] = f2bf(r);
    }
    Frag2 f;
    f.h = __builtin_bit_cast(bf16x8, uh);
    f.l = __builtin_bit_cast(bf16x8, ul);
    return f;
}

static __device__ inline bf16x8 pack_bf8(float4 x0, float4 x1) {
    float v[8] = {x0.x, x0.y, x0.z, x0.w, x1.x, x1.y, x1.z, x1.w};
    ushort8 u;
#pragma unroll
    for (int j = 0; j < 8; ++j) u[j] = f2bf(v[j]);
    return __builtin_bit_cast(bf16x8, u);
}

static __device__ inline bf16x8 load_bf8(const float* __restrict__ p) {
    float4 x0 = *reinterpret_cast<const float4*>(p);
    float4 x1 = *reinterpret_cast<const float4*>(p + 4);
    return pack_bf8(x0, x1);
}

static __device__ inline bf16x8 load_bf8_strided(const float* __restrict__ p, int stride) {
    ushort8 u;
#pragma unroll
    for (int j = 0; j < 8; ++j) u[j] = f2bf(p[(size_t)j * stride]);
    return __builtin_bit_cast(bf16x8, u);
}

#define MFMA(a, b, c) __builtin_amdgcn_mfma_f32_16x16x32_bf16((a), (b), (c), 0, 0, 0)

// async global -> LDS, 16B per lane; lds dest is wave-uniform base + lane*16
#define GLLD(g, s)                                                              \
    __builtin_amdgcn_global_load_lds(                                           \
        (const __attribute__((address_space(1))) void*)(g),                     \
        (__attribute__((address_space(3))) void*)(s), 16, 0, 0)

// stage a 64x64 fp32 tile (rows at src0 + row*DH) into buf[b]; WAVE-PRIVATE:
// wave w stages rows [w*16, w*16+16) and later reads only those rows.
// source pre-swizzled (chunk ^= row&7) so linear LDS + swizzled reads match.
#define STAGE64(src0, b)                                                        \
    do {                                                                        \
        _Pragma("unroll")                                                       \
        for (int j_ = 0; j_ < 4; ++j_) {                                        \
            const int idx_ = w * 256 + j_ * 64 + l;                             \
            const int row_ = idx_ >> 4;                                         \
            const int g_ = (idx_ & 15) ^ (row_ & 7);                            \
            GLLD((src0) + (size_t)row_ * DH + g_ * 4,                           \
                 &buf[b][w * 256 + j_ * 64]);                                   \
        }                                                                       \
    } while (0)

#define WAITVN(n)                                                               \
    do {                                                                        \
        asm volatile("s_waitcnt vmcnt(" #n ")" ::: "memory");                   \
        __builtin_amdgcn_sched_barrier(0);                                      \
    } while (0)

// ---------------- K1: content scores Q@K^T * scale -> P (zeros above diag).
// Block = (q-tile 64, bh). Barrier-free: LDS is wave-private, counted vmcnt.
__global__ __launch_bounds__(256, 4) void k_scores(const float* __restrict__ qp,
                                                   const float* __restrict__ kp,
                                                   float* __restrict__ P) {
    __shared__ float4 buf[2][1024];
    const int qt = 15 - (int)blockIdx.x;  // big first
    const int bh = blockIdx.y;
    const int tid = threadIdx.x;
    const int w = tid >> 6, l = tid & 63;
    const int lm = l & 15, lg = l >> 4;
    const int q0 = qt * 64;

    Frag2 qh0[4], qh1[4];  // pre-scaled by SCALE
#pragma unroll
    for (int nt = 0; nt < 4; ++nt) {
        const float* qrow = qp + ((size_t)bh * SQ + q0 + nt * 16 + lm) * DH + lg * 8;
        qh0[nt] = load_split(qrow, SCALE);
        qh1[nt] = load_split(qrow + 32, SCALE);
    }
    const float* kb = kp + (size_t)bh * SK * DH;
    const int nt_ = qt + 1;

    STAGE64(kb, 0);
#pragma unroll 1
    for (int t = 0; t < nt_; ++t) {
        if (t + 1 < nt_) {
            STAGE64(kb + (size_t)(t + 1) * 64 * DH, (t + 1) & 1);
            WAITVN(4);  // stage(t)+stores(t-1) landed; stage(t+1) in flight
        } else {
            WAITVN(0);
        }
        const float4* L = buf[t & 1];
        const int R = w * 16 + lm;
        const int sw = R & 7;
        float4 f0 = L[R * 16 + ((2 * lg) ^ sw)];
        float4 f1 = L[R * 16 + ((2 * lg + 1) ^ sw)];
        float4 f2 = L[R * 16 + ((8 + 2 * lg) ^ sw)];
        float4 f3 = L[R * 16 + ((9 + 2 * lg) ^ sw)];
        bf16x8 alo = pack_bf8(f0, f1);
        bf16x8 ahi = pack_bf8(f2, f3);
        const int kq = t * 64 + w * 16 + lg * 4;
        const bool diag = (t == qt);
#pragma unroll
        for (int nt = 0; nt < 4; ++nt) {
            f32x4 acc = {0.f, 0.f, 0.f, 0.f};
            acc = MFMA(alo, qh0[nt].h, acc);
            acc = MFMA(alo, qh0[nt].l, acc);
            acc = MFMA(ahi, qh1[nt].h, acc);
            acc = MFMA(ahi, qh1[nt].l, acc);
            const int qe = q0 + nt * 16 + lm;
            float ov[4];
#pragma unroll
            for (int r = 0; r < 4; ++r)
                ov[r] = (!diag || (kq + r <= qe)) ? acc[r] : 0.f;
            float4 o;
            o.x = ov[0]; o.y = ov[1]; o.z = ov[2]; o.w = ov[3];
            *reinterpret_cast<float4*>(&P[((size_t)bh * SQ + qe) * SK + kq]) = o;
        }
    }
    // zero-fill tiles fully above the diagonal
    const float4 z = {0.f, 0.f, 0.f, 0.f};
#pragma unroll 1
    for (int t = nt_; t < 16; ++t) {
        const int kq = t * 64 + w * 16 + lg * 4;
#pragma unroll
        for (int nt = 0; nt < 4; ++nt) {
            const int qe = q0 + nt * 16 + lm;
            *reinterpret_cast<float4*>(&P[((size_t)bh * SQ + qe) * SK + kq]) = z;
        }
    }
}

// ---------------- K2: fused rel+exp+normalize+P@bigr_v. Block per q.
__global__ __launch_bounds__(256, 4) void k_rel_pr(const float* __restrict__ query,
                                                   const float* __restrict__ bigr_k,
                                                   const float* __restrict__ bigr_v,
                                                   float* __restrict__ P,
                                                   float* __restrict__ out) {
    __shared__ float4 buf[2][1024];
    __shared__ float red[4][64];
    __shared__ float rsum[64];
    const int q = SQ - 1 - (int)blockIdx.x;  // big rows first
    const int KE = q + 1;
    const int nt_ = (KE + 63) >> 6;
    const int tid = threadIdx.x;
    const int w = tid >> 6, l = tid & 63;
    const int lm = l & 15, lg = l >> 4;

    // ---- pass 1: e = exp(content + rel), row sums; 2-deep vmem pipeline ----
    Frag2 qh0[4], qh1[4];  // pre-scaled
    float* prow[4];
#pragma unroll
    for (int nt = 0; nt < 4; ++nt) {
        const int bh = nt * 16 + lm;
        const float* qrow = query + ((size_t)bh * SQ + q) * DH + lg * 8;
        qh0[nt] = load_split(qrow, SCALE);
        qh1[nt] = load_split(qrow + 32, SCALE);
        prow[nt] = P + ((size_t)bh * SQ + q) * SK;
    }
    const float* bk = bigr_k + (size_t)q * SK * DH;
    float lsum[4] = {0.f, 0.f, 0.f, 0.f};

    // prologue: stage(0) + pc(0)
    STAGE64(bk, 0);
    float4 pcA[4], pcB[4];
    {
        const int kq0 = w * 16 + lg * 4;
#pragma unroll
        for (int nt = 0; nt < 4; ++nt)
            pcA[nt] = *reinterpret_cast<const float4*>(prow[nt] + kq0);
    }
#pragma unroll 1
    for (int t = 0; t < nt_; ++t) {
        // prefetch tile t+1 (clamped at tail -> uniform vmem counts)
        const int tn = (t + 1 < nt_) ? (t + 1) : t;
        STAGE64(bk + (size_t)tn * 64 * DH, (t + 1) & 1);
        const int kqn = tn * 64 + w * 16 + lg * 4;
        if (t & 1) {
#pragma unroll
            for (int nt = 0; nt < 4; ++nt)
                pcA[nt] = *reinterpret_cast<const float4*>(prow[nt] + kqn);
        } else {
#pragma unroll
            for (int nt = 0; nt < 4; ++nt)
                pcB[nt] = *reinterpret_cast<const float4*>(prow[nt] + kqn);
        }
        WAITVN(8);  // retire stage(t)+pc(t)+stores(t-1); keep stage(t+1)+pc(t+1)
        const float4* L = buf[t & 1];
        const int R = w * 16 + lm;
        const int sw = R & 7;
        float4 f0 = L[R * 16 + ((2 * lg) ^ sw)];
        float4 f1 = L[R * 16 + ((2 * lg + 1) ^ sw)];
        float4 f2 = L[R * 16 + ((8 + 2 * lg) ^ sw)];
        float4 f3 = L[R * 16 + ((9 + 2 * lg) ^ sw)];
        bf16x8 alo = pack_bf8(f0, f1);
        bf16x8 ahi = pack_bf8(f2, f3);
        const int kq = t * 64 + w * 16 + lg * 4;
#pragma unroll
        for (int nt = 0; nt < 4; ++nt) {
            f32x4 acc = {0.f, 0.f, 0.f, 0.f};
            acc = MFMA(alo, qh0[nt].h, acc);
            acc = MFMA(alo, qh0[nt].l, acc);
            acc = MFMA(ahi, qh1[nt].h, acc);
            acc = MFMA(ahi, qh1[nt].l, acc);
            const float4 c = (t & 1) ? pcB[nt] : pcA[nt];
            float cv[4] = {c.x, c.y, c.z, c.w};
            float ov[4];
#pragma unroll
            for (int r = 0; r < 4; ++r) {
                float e = (kq + r < KE) ? __expf(cv[r] + acc[r]) : 0.f;
                ov[r] = e;
                lsum[nt] += e;
            }
            float4 o;
            o.x = ov[0]; o.y = ov[1]; o.z = ov[2]; o.w = ov[3];
            *reinterpret_cast<float4*>(prow[nt] + kq) = o;
        }
    }

    // ---- row-sum reduce -> recip in LDS ----
#pragma unroll
    for (int nt = 0; nt < 4; ++nt) {
        float v = lsum[nt];
        v += __shfl_xor(v, 16);
        v += __shfl_xor(v, 32);
        if (l < 16) red[w][nt * 16 + l] = v;
    }
    __syncthreads();
    if (tid < 64)
        rsum[tid] = 1.0f / (red[0][tid] + red[1][tid] + red[2][tid] + red[3][tid]);
    __syncthreads();

    // ---- pass 2: normalize P in place + out = Pn @ bigr_v[q]; no barriers ----
    const int bh0 = w * 16;
    const float* bv = bigr_v + (size_t)q * SK * DH;
    float* arow0 = P + ((size_t)(bh0 + lm) * SQ + q) * SK + lg * 8;
    const float nrm = rsum[bh0 + lm];
    f32x4 acc[4] = {{0.f,0.f,0.f,0.f},{0.f,0.f,0.f,0.f},{0.f,0.f,0.f,0.f},{0.f,0.f,0.f,0.f}};
#pragma unroll 2
    for (int k0 = 0; k0 < KE; k0 += 32) {
        float* arow = arow0 + k0;
        float4 x0 = *reinterpret_cast<const float4*>(arow);
        float4 x1 = *reinterpret_cast<const float4*>(arow + 4);
        float4 y0 = {x0.x * nrm, x0.y * nrm, x0.z * nrm, x0.w * nrm};
        float4 y1 = {x1.x * nrm, x1.y * nrm, x1.z * nrm, x1.w * nrm};
        *reinterpret_cast<float4*>(arow) = y0;       // final normalized p_attn
        *reinterpret_cast<float4*>(arow + 4) = y1;
        bf16x8 a = pack_bf8(y0, y1);
#pragma unroll
        for (int nt = 0; nt < 4; ++nt) {
            const float* bcol = bv + (size_t)(k0 + lg * 8) * DH + nt * 16 + lm;
            bf16x8 b = load_bf8_strided(bcol, DH);
            acc[nt] = MFMA(a, b, acc[nt]);
        }
    }
#pragma unroll
    for (int nt = 0; nt < 4; ++nt)
#pragma unroll
        for (int r = 0; r < 4; ++r)
            out[((size_t)(bh0 + lg * 4 + r) * SQ + q) * DH + nt * 16 + lm] = acc[nt][r];
}

// ---------------- K3: out += Pn @ V (per bh, q-tiles of 64)
__global__ __launch_bounds__(256) void k_pv(const float* __restrict__ P,
                                            const float* __restrict__ V,
                                            float* __restrict__ out) {
    const int qt = 15 - (int)blockIdx.x;  // big tiles first
    const int bh = blockIdx.y;
    const int tid = threadIdx.x;
    const int w = tid >> 6, l = tid & 63;
    const int lm = l & 15, lg = l >> 4;
    const int q0 = qt * 64 + w * 16;

    f32x4 acc[4] = {{0.f,0.f,0.f,0.f},{0.f,0.f,0.f,0.f},{0.f,0.f,0.f,0.f},{0.f,0.f,0.f,0.f}};
    const int kend = q0 + 16;
    for (int k0 = 0; k0 < kend; k0 += 32) {
        const float* arow = P + ((size_t)bh * SQ + q0 + lm) * SK + k0 + lg * 8;
        bf16x8 a = load_bf8(arow);
#pragma unroll
        for (int nt = 0; nt < 4; ++nt) {
            const float* bcol = V + ((size_t)bh * SK + k0 + lg * 8) * DH + nt * 16 + lm;
            bf16x8 b = load_bf8_strided(bcol, DH);
            acc[nt] = MFMA(a, b, acc[nt]);
        }
    }
#pragma unroll
    for (int nt = 0; nt < 4; ++nt)
#pragma unroll
        for (int r = 0; r < 4; ++r)
            out[((size_t)bh * SQ + q0 + lg * 4 + r) * DH + nt * 16 + lm] += acc[nt][r];
}

extern "C" void kernel_launch(void* const* d_in, const int* in_sizes, int n_in,
                              void* d_out, int out_size, void* d_ws, size_t ws_size,
                              hipStream_t stream) {
    const float* query  = (const float*)d_in[0];
    const float* key    = (const float*)d_in[1];
    const float* value  = (const float*)d_in[2];
    const float* bigr_k = (const float*)d_in[3];
    const float* bigr_v = (const float*)d_in[4];
    float* out = (float*)d_out;                       // BH*SQ*DH
    float* P   = out + (size_t)BH * SQ * DH;          // BH*SQ*SK

    k_scores<<<dim3(16, BH), 256, 0, stream>>>(query, key, P);
    k_rel_pr<<<dim3(SQ), 256, 0, stream>>>(query, bigr_k, bigr_v, P, out);
    k_pv<<<dim3(16, BH), 256, 0, stream>>>(P, value, out);
}

// Round 14
// 518.391 us; speedup vs baseline: 1.3902x; 1.1388x over previous
//
#include <hip/hip_runtime.h>
#include <hip/hip_bf16.h>

// Relative-position causal attention, B=4 H=16 Q=K=1024 D=64 (fp32 in/out).
// d_out = [output (BH*Q*D) | p_attn (BH*Q*K)] fp32.
// K1 k_scores: content scores (R9, LDS-staged GEMM, counted vmcnt).
// K2 k_rel_exp: pass1 rel+exp (R9 schedule, barrier-free, 32KB LDS, partial
//               row sums per wave -> d_ws).
// K3 k_pr: normalize P in place (final p_attn) + out = Pn@bigr_v[q]; no LDS,
//          high occupancy, ascending q.
// K4 k_pv: out += Pn @ V (R9).

#define BH 64
#define SQ 1024
#define SK 1024
#define DH 64
#define SCALE 0.125f

typedef __attribute__((ext_vector_type(4))) float f32x4;
typedef __attribute__((ext_vector_type(8))) unsigned short ushort8;
typedef __attribute__((ext_vector_type(8))) __bf16 bf16x8;

static __device__ inline unsigned short f2bf(float x) {
    unsigned u = __float_as_uint(x);
    unsigned r = u + 0x7FFFu + ((u >> 16) & 1u);
    return (unsigned short)(r >> 16);
}
static __device__ inline float bf2f(unsigned short s) {
    return __uint_as_float(((unsigned)s) << 16);
}

struct Frag2 { bf16x8 h, l; };

// Load 8 fp32, scale, split into hi/lo bf16 fragments (hi+lo == scaled value).
static __device__ inline Frag2 load_split(const float* __restrict__ p, float scale) {
    float4 x0 = *reinterpret_cast<const float4*>(p);
    float4 x1 = *reinterpret_cast<const float4*>(p + 4);
    float v[8] = {x0.x, x0.y, x0.z, x0.w, x1.x, x1.y, x1.z, x1.w};
    ushort8 uh, ul;
#pragma unroll
    for (int j = 0; j < 8; ++j) {
        float s = v[j] * scale;
        unsigned short h = f2bf(s);
        float r = s - bf2f(h);
        uh[j] = h;
        ul[j] = f2bf(r);
    }
    Frag2 f;
    f.h = __builtin_bit_cast(bf16x8, uh);
    f.l = __builtin_bit_cast(bf16x8, ul);
    return f;
}

static __device__ inline bf16x8 pack_bf8(float4 x0, float4 x1) {
    float v[8] = {x0.x, x0.y, x0.z, x0.w, x1.x, x1.y, x1.z, x1.w};
    ushort8 u;
#pragma unroll
    for (int j = 0; j < 8; ++j) u[j] = f2bf(v[j]);
    return __builtin_bit_cast(bf16x8, u);
}

static __device__ inline bf16x8 load_bf8(const float* __restrict__ p) {
    float4 x0 = *reinterpret_cast<const float4*>(p);
    float4 x1 = *reinterpret_cast<const float4*>(p + 4);
    return pack_bf8(x0, x1);
}

static __device__ inline bf16x8 load_bf8_strided(const float* __restrict__ p, int stride) {
    ushort8 u;
#pragma unroll
    for (int j = 0; j < 8; ++j) u[j] = f2bf(p[(size_t)j * stride]);
    return __builtin_bit_cast(bf16x8, u);
}

#define MFMA(a, b, c) __builtin_amdgcn_mfma_f32_16x16x32_bf16((a), (b), (c), 0, 0, 0)

// async global -> LDS, 16B per lane; lds dest is wave-uniform base + lane*16
#define GLLD(g, s)                                                              \
    __builtin_amdgcn_global_load_lds(                                           \
        (const __attribute__((address_space(1))) void*)(g),                     \
        (__attribute__((address_space(3))) void*)(s), 16, 0, 0)

// stage a 64x64 fp32 tile (rows at src0 + row*DH) into buf[b]; WAVE-PRIVATE:
// wave w stages rows [w*16, w*16+16) and later reads only those rows.
// source pre-swizzled (chunk ^= row&7) so linear LDS + swizzled reads match.
#define STAGE64(src0, b)                                                        \
    do {                                                                        \
        _Pragma("unroll")                                                       \
        for (int j_ = 0; j_ < 4; ++j_) {                                        \
            const int idx_ = w * 256 + j_ * 64 + l;                             \
            const int row_ = idx_ >> 4;                                         \
            const int g_ = (idx_ & 15) ^ (row_ & 7);                            \
            GLLD((src0) + (size_t)row_ * DH + g_ * 4,                           \
                 &buf[b][w * 256 + j_ * 64]);                                   \
        }                                                                       \
    } while (0)

#define WAITVN(n)                                                               \
    do {                                                                        \
        asm volatile("s_waitcnt vmcnt(" #n ")" ::: "memory");                   \
        __builtin_amdgcn_sched_barrier(0);                                      \
    } while (0)

// ---------------- K1: content scores Q@K^T * scale -> P (zeros above diag).
// Block = (q-tile 64, bh). Barrier-free: LDS is wave-private, counted vmcnt.
__global__ __launch_bounds__(256, 4) void k_scores(const float* __restrict__ qp,
                                                   const float* __restrict__ kp,
                                                   float* __restrict__ P) {
    __shared__ float4 buf[2][1024];
    const int qt = 15 - (int)blockIdx.x;  // big first
    const int bh = blockIdx.y;
    const int tid = threadIdx.x;
    const int w = tid >> 6, l = tid & 63;
    const int lm = l & 15, lg = l >> 4;
    const int q0 = qt * 64;

    Frag2 qh0[4], qh1[4];  // pre-scaled by SCALE
#pragma unroll
    for (int nt = 0; nt < 4; ++nt) {
        const float* qrow = qp + ((size_t)bh * SQ + q0 + nt * 16 + lm) * DH + lg * 8;
        qh0[nt] = load_split(qrow, SCALE);
        qh1[nt] = load_split(qrow + 32, SCALE);
    }
    const float* kb = kp + (size_t)bh * SK * DH;
    const int nt_ = qt + 1;

    STAGE64(kb, 0);
#pragma unroll 1
    for (int t = 0; t < nt_; ++t) {
        if (t + 1 < nt_) {
            STAGE64(kb + (size_t)(t + 1) * 64 * DH, (t + 1) & 1);
            WAITVN(4);  // stage(t)+stores(t-1) landed; stage(t+1) in flight
        } else {
            WAITVN(0);
        }
        const float4* L = buf[t & 1];
        const int R = w * 16 + lm;
        const int sw = R & 7;
        float4 f0 = L[R * 16 + ((2 * lg) ^ sw)];
        float4 f1 = L[R * 16 + ((2 * lg + 1) ^ sw)];
        float4 f2 = L[R * 16 + ((8 + 2 * lg) ^ sw)];
        float4 f3 = L[R * 16 + ((9 + 2 * lg) ^ sw)];
        bf16x8 alo = pack_bf8(f0, f1);
        bf16x8 ahi = pack_bf8(f2, f3);
        const int kq = t * 64 + w * 16 + lg * 4;
        const bool diag = (t == qt);
#pragma unroll
        for (int nt = 0; nt < 4; ++nt) {
            f32x4 acc = {0.f, 0.f, 0.f, 0.f};
            acc = MFMA(alo, qh0[nt].h, acc);
            acc = MFMA(alo, qh0[nt].l, acc);
            acc = MFMA(ahi, qh1[nt].h, acc);
            acc = MFMA(ahi, qh1[nt].l, acc);
            const int qe = q0 + nt * 16 + lm;
            float ov[4];
#pragma unroll
            for (int r = 0; r < 4; ++r)
                ov[r] = (!diag || (kq + r <= qe)) ? acc[r] : 0.f;
            float4 o;
            o.x = ov[0]; o.y = ov[1]; o.z = ov[2]; o.w = ov[3];
            *reinterpret_cast<float4*>(&P[((size_t)bh * SQ + qe) * SK + kq]) = o;
        }
    }
    // zero-fill tiles fully above the diagonal
    const float4 z = {0.f, 0.f, 0.f, 0.f};
#pragma unroll 1
    for (int t = nt_; t < 16; ++t) {
        const int kq = t * 64 + w * 16 + lg * 4;
#pragma unroll
        for (int nt = 0; nt < 4; ++nt) {
            const int qe = q0 + nt * 16 + lm;
            *reinterpret_cast<float4*>(&P[((size_t)bh * SQ + qe) * SK + kq]) = z;
        }
    }
}

// ---------------- K2: pass1 rel+exp. Block per q (descending). Barrier-free;
// per-wave partial row sums -> ws[q][w][bh]. LDS = exactly 32 KB.
__global__ __launch_bounds__(256, 4) void k_rel_exp(const float* __restrict__ query,
                                                    const float* __restrict__ bigr_k,
                                                    float* __restrict__ P,
                                                    float* __restrict__ partial) {
    __shared__ float4 buf[2][1024];  // 32 KB
    const int q = SQ - 1 - (int)blockIdx.x;  // big rows first
    const int KE = q + 1;
    const int nt_ = (KE + 63) >> 6;
    const int tid = threadIdx.x;
    const int w = tid >> 6, l = tid & 63;
    const int lm = l & 15, lg = l >> 4;

    Frag2 qh0[4], qh1[4];  // pre-scaled
    float* prow[4];
#pragma unroll
    for (int nt = 0; nt < 4; ++nt) {
        const int bh = nt * 16 + lm;
        const float* qrow = query + ((size_t)bh * SQ + q) * DH + lg * 8;
        qh0[nt] = load_split(qrow, SCALE);
        qh1[nt] = load_split(qrow + 32, SCALE);
        prow[nt] = P + ((size_t)bh * SQ + q) * SK;
    }
    const float* bk = bigr_k + (size_t)q * SK * DH;
    float lsum[4] = {0.f, 0.f, 0.f, 0.f};

    STAGE64(bk, 0);
#pragma unroll 1
    for (int t = 0; t < nt_; ++t) {
        const int kq = t * 64 + w * 16 + lg * 4;
        float4 pc[4];
#pragma unroll
        for (int nt = 0; nt < 4; ++nt)
            pc[nt] = *reinterpret_cast<const float4*>(prow[nt] + kq);
        if (t + 1 < nt_) {
            STAGE64(bk + (size_t)(t + 1) * 64 * DH, (t + 1) & 1);
            WAITVN(4);  // stage(t)+pc landed; stage(t+1) in flight
        } else {
            WAITVN(0);
        }
        const float4* L = buf[t & 1];
        const int R = w * 16 + lm;
        const int sw = R & 7;
        float4 f0 = L[R * 16 + ((2 * lg) ^ sw)];
        float4 f1 = L[R * 16 + ((2 * lg + 1) ^ sw)];
        float4 f2 = L[R * 16 + ((8 + 2 * lg) ^ sw)];
        float4 f3 = L[R * 16 + ((9 + 2 * lg) ^ sw)];
        bf16x8 alo = pack_bf8(f0, f1);
        bf16x8 ahi = pack_bf8(f2, f3);
#pragma unroll
        for (int nt = 0; nt < 4; ++nt) {
            f32x4 acc = {0.f, 0.f, 0.f, 0.f};
            acc = MFMA(alo, qh0[nt].h, acc);
            acc = MFMA(alo, qh0[nt].l, acc);
            acc = MFMA(ahi, qh1[nt].h, acc);
            acc = MFMA(ahi, qh1[nt].l, acc);
            const float4 c = pc[nt];
            float cv[4] = {c.x, c.y, c.z, c.w};
            float ov[4];
#pragma unroll
            for (int r = 0; r < 4; ++r) {
                float e = (kq + r < KE) ? __expf(cv[r] + acc[r]) : 0.f;
                ov[r] = e;
                lsum[nt] += e;
            }
            float4 o;
            o.x = ov[0]; o.y = ov[1]; o.z = ov[2]; o.w = ov[3];
            *reinterpret_cast<float4*>(prow[nt] + kq) = o;
        }
    }

    // per-wave row sums -> ws[q][w][bh] (no cross-wave reduce, no barriers)
#pragma unroll
    for (int nt = 0; nt < 4; ++nt) {
        float v = lsum[nt];
        v += __shfl_xor(v, 16);
        v += __shfl_xor(v, 32);
        if (l < 16)
            partial[((size_t)q * 4 + w) * 64 + nt * 16 + l] = v;
    }
}

// ---------------- K3: normalize P in place + out = Pn @ bigr_v[q].
// Block per q (ascending: freshest k_rel_exp rows first). No LDS.
__global__ __launch_bounds__(256) void k_pr(const float* __restrict__ bigr_v,
                                            const float* __restrict__ partial,
                                            float* __restrict__ P,
                                            float* __restrict__ out) {
    const int q = (int)blockIdx.x;
    const int KE = q + 1;
    const int tid = threadIdx.x;
    const int w = tid >> 6, l = tid & 63;
    const int lm = l & 15, lg = l >> 4;
    const int bh0 = w * 16;

    // nrm for this lane's A-row (bh = bh0+lm): sum the 4 per-wave partials
    const float* pp = partial + (size_t)q * 256 + bh0 + lm;
    const float nrm = 1.0f / (pp[0] + pp[64] + pp[128] + pp[192]);

    const float* bv = bigr_v + (size_t)q * SK * DH;
    float* arow0 = P + ((size_t)(bh0 + lm) * SQ + q) * SK + lg * 8;
    f32x4 acc[4] = {{0.f,0.f,0.f,0.f},{0.f,0.f,0.f,0.f},{0.f,0.f,0.f,0.f},{0.f,0.f,0.f,0.f}};
#pragma unroll 2
    for (int k0 = 0; k0 < KE; k0 += 32) {
        float* arow = arow0 + k0;
        float4 x0 = *reinterpret_cast<const float4*>(arow);
        float4 x1 = *reinterpret_cast<const float4*>(arow + 4);
        float4 y0 = {x0.x * nrm, x0.y * nrm, x0.z * nrm, x0.w * nrm};
        float4 y1 = {x1.x * nrm, x1.y * nrm, x1.z * nrm, x1.w * nrm};
        *reinterpret_cast<float4*>(arow) = y0;       // final normalized p_attn
        *reinterpret_cast<float4*>(arow + 4) = y1;
        bf16x8 a = pack_bf8(y0, y1);
#pragma unroll
        for (int nt = 0; nt < 4; ++nt) {
            const float* bcol = bv + (size_t)(k0 + lg * 8) * DH + nt * 16 + lm;
            bf16x8 b = load_bf8_strided(bcol, DH);
            acc[nt] = MFMA(a, b, acc[nt]);
        }
    }
#pragma unroll
    for (int nt = 0; nt < 4; ++nt)
#pragma unroll
        for (int r = 0; r < 4; ++r)
            out[((size_t)(bh0 + lg * 4 + r) * SQ + q) * DH + nt * 16 + lm] = acc[nt][r];
}

// ---------------- K4: out += Pn @ V (per bh, q-tiles of 64)
__global__ __launch_bounds__(256) void k_pv(const float* __restrict__ P,
                                            const float* __restrict__ V,
                                            float* __restrict__ out) {
    const int qt = 15 - (int)blockIdx.x;  // big tiles first
    const int bh = blockIdx.y;
    const int tid = threadIdx.x;
    const int w = tid >> 6, l = tid & 63;
    const int lm = l & 15, lg = l >> 4;
    const int q0 = qt * 64 + w * 16;

    f32x4 acc[4] = {{0.f,0.f,0.f,0.f},{0.f,0.f,0.f,0.f},{0.f,0.f,0.f,0.f},{0.f,0.f,0.f,0.f}};
    const int kend = q0 + 16;
    for (int k0 = 0; k0 < kend; k0 += 32) {
        const float* arow = P + ((size_t)bh * SQ + q0 + lm) * SK + k0 + lg * 8;
        bf16x8 a = load_bf8(arow);
#pragma unroll
        for (int nt = 0; nt < 4; ++nt) {
            const float* bcol = V + ((size_t)bh * SK + k0 + lg * 8) * DH + nt * 16 + lm;
            bf16x8 b = load_bf8_strided(bcol, DH);
            acc[nt] = MFMA(a, b, acc[nt]);
        }
    }
#pragma unroll
    for (int nt = 0; nt < 4; ++nt)
#pragma unroll
        for (int r = 0; r < 4; ++r)
            out[((size_t)bh * SQ + q0 + lg * 4 + r) * DH + nt * 16 + lm] += acc[nt][r];
}

extern "C" void kernel_launch(void* const* d_in, const int* in_sizes, int n_in,
                              void* d_out, int out_size, void* d_ws, size_t ws_size,
                              hipStream_t stream) {
    const float* query  = (const float*)d_in[0];
    const float* key    = (const float*)d_in[1];
    const float* value  = (const float*)d_in[2];
    const float* bigr_k = (const float*)d_in[3];
    const float* bigr_v = (const float*)d_in[4];
    float* out = (float*)d_out;                       // BH*SQ*DH
    float* P   = out + (size_t)BH * SQ * DH;          // BH*SQ*SK
    float* partial = (float*)d_ws;                    // [SQ][4][BH] fp32 = 1 MB

    k_scores<<<dim3(16, BH), 256, 0, stream>>>(query, key, P);
    k_rel_exp<<<dim3(SQ), 256, 0, stream>>>(query, bigr_k, P, partial);
    k_pr<<<dim3(SQ), 256, 0, stream>>>(bigr_v, partial, P, out);
    k_pv<<<dim3(16, BH), 256, 0, stream>>>(P, value, out);
}

// Round 15
// 469.332 us; speedup vs baseline: 1.5356x; 1.1045x over previous
//
#include <hip/hip_runtime.h>
#include <hip/hip_bf16.h>

// Relative-position causal attention, B=4 H=16 Q=K=1024 D=64 (fp32 in/out).
// d_out = [output (BH*Q*D) | p_attn (BH*Q*K)] fp32.
// K1 k_scores: content scores (LDS-staged GEMM, counted vmcnt).
// K2 k_rel_pv: rel+exp writes e to P AND accumulates out=Pr@bigr_v on the fly
//              (C-layout == A-layout identity, half-K MFMA); rowsum recip -> ws.
// K3 k_pv: read e, write Pn=e*recip in place (final p_attn), out += Pn@V.

#define BH 64
#define SQ 1024
#define SK 1024
#define DH 64
#define SCALE 0.125f

typedef __attribute__((ext_vector_type(4))) float f32x4;
typedef __attribute__((ext_vector_type(8))) unsigned short ushort8;
typedef __attribute__((ext_vector_type(8))) __bf16 bf16x8;

static __device__ inline unsigned short f2bf(float x) {
    unsigned u = __float_as_uint(x);
    unsigned r = u + 0x7FFFu + ((u >> 16) & 1u);
    return (unsigned short)(r >> 16);
}
static __device__ inline float bf2f(unsigned short s) {
    return __uint_as_float(((unsigned)s) << 16);
}

struct Frag2 { bf16x8 h, l; };

// Load 8 fp32, scale, split into hi/lo bf16 fragments (hi+lo == scaled value).
static __device__ inline Frag2 load_split(const float* __restrict__ p, float scale) {
    float4 x0 = *reinterpret_cast<const float4*>(p);
    float4 x1 = *reinterpret_cast<const float4*>(p + 4);
    float v[8] = {x0.x, x0.y, x0.z, x0.w, x1.x, x1.y, x1.z, x1.w};
    ushort8 uh, ul;
#pragma unroll
    for (int j = 0; j < 8; ++j) {
        float s = v[j] * scale;
        unsigned short h = f2bf(s);
        float r = s - bf2f(h);
        uh[j] = h;
        ul[j] = f2bf(r);
    }
    Frag2 f;
    f.h = __builtin_bit_cast(bf16x8, uh);
    f.l = __builtin_bit_cast(bf16x8, ul);
    return f;
}

static __device__ inline bf16x8 pack_bf8(float4 x0, float4 x1) {
    float v[8] = {x0.x, x0.y, x0.z, x0.w, x1.x, x1.y, x1.z, x1.w};
    ushort8 u;
#pragma unroll
    for (int j = 0; j < 8; ++j) u[j] = f2bf(v[j]);
    return __builtin_bit_cast(bf16x8, u);
}

static __device__ inline bf16x8 load_bf8(const float* __restrict__ p) {
    float4 x0 = *reinterpret_cast<const float4*>(p);
    float4 x1 = *reinterpret_cast<const float4*>(p + 4);
    return pack_bf8(x0, x1);
}

static __device__ inline bf16x8 load_bf8_strided(const float* __restrict__ p, int stride) {
    ushort8 u;
#pragma unroll
    for (int j = 0; j < 8; ++j) u[j] = f2bf(p[(size_t)j * stride]);
    return __builtin_bit_cast(bf16x8, u);
}

#define MFMA(a, b, c) __builtin_amdgcn_mfma_f32_16x16x32_bf16((a), (b), (c), 0, 0, 0)

// async global -> LDS, 16B per lane; lds dest is wave-uniform base + lane*16
#define GLLD(g, s)                                                              \
    __builtin_amdgcn_global_load_lds(                                           \
        (const __attribute__((address_space(1))) void*)(g),                     \
        (__attribute__((address_space(3))) void*)(s), 16, 0, 0)

// stage a 64x64 fp32 tile (rows at src0 + row*DH) into buf[b]; WAVE-PRIVATE:
// wave w stages rows [w*16, w*16+16) and later reads only those rows.
// source pre-swizzled (chunk ^= row&7) so linear LDS + swizzled reads match.
#define STAGE64(src0, b)                                                        \
    do {                                                                        \
        _Pragma("unroll")                                                       \
        for (int j_ = 0; j_ < 4; ++j_) {                                        \
            const int idx_ = w * 256 + j_ * 64 + l;                             \
            const int row_ = idx_ >> 4;                                         \
            const int g_ = (idx_ & 15) ^ (row_ & 7);                            \
            GLLD((src0) + (size_t)row_ * DH + g_ * 4,                           \
                 &buf[b][w * 256 + j_ * 64]);                                   \
        }                                                                       \
    } while (0)

#define WAITVN(n)                                                               \
    do {                                                                        \
        asm volatile("s_waitcnt vmcnt(" #n ")" ::: "memory");                   \
        __builtin_amdgcn_sched_barrier(0);                                      \
    } while (0)

// ---------------- K1: content scores Q@K^T * scale -> P (zeros above diag).
// Block = (q-tile 64, bh). Barrier-free: LDS is wave-private, counted vmcnt.
__global__ __launch_bounds__(256, 4) void k_scores(const float* __restrict__ qp,
                                                   const float* __restrict__ kp,
                                                   float* __restrict__ P) {
    __shared__ float4 buf[2][1024];
    const int qt = 15 - (int)blockIdx.x;  // big first
    const int bh = blockIdx.y;
    const int tid = threadIdx.x;
    const int w = tid >> 6, l = tid & 63;
    const int lm = l & 15, lg = l >> 4;
    const int q0 = qt * 64;

    Frag2 qh0[4], qh1[4];  // pre-scaled by SCALE
#pragma unroll
    for (int nt = 0; nt < 4; ++nt) {
        const float* qrow = qp + ((size_t)bh * SQ + q0 + nt * 16 + lm) * DH + lg * 8;
        qh0[nt] = load_split(qrow, SCALE);
        qh1[nt] = load_split(qrow + 32, SCALE);
    }
    const float* kb = kp + (size_t)bh * SK * DH;
    const int nt_ = qt + 1;

    STAGE64(kb, 0);
#pragma unroll 1
    for (int t = 0; t < nt_; ++t) {
        if (t + 1 < nt_) {
            STAGE64(kb + (size_t)(t + 1) * 64 * DH, (t + 1) & 1);
            WAITVN(4);  // stage(t)+stores(t-1) landed; stage(t+1) in flight
        } else {
            WAITVN(0);
        }
        const float4* L = buf[t & 1];
        const int R = w * 16 + lm;
        const int sw = R & 7;
        float4 f0 = L[R * 16 + ((2 * lg) ^ sw)];
        float4 f1 = L[R * 16 + ((2 * lg + 1) ^ sw)];
        float4 f2 = L[R * 16 + ((8 + 2 * lg) ^ sw)];
        float4 f3 = L[R * 16 + ((9 + 2 * lg) ^ sw)];
        bf16x8 alo = pack_bf8(f0, f1);
        bf16x8 ahi = pack_bf8(f2, f3);
        const int kq = t * 64 + w * 16 + lg * 4;
        const bool diag = (t == qt);
#pragma unroll
        for (int nt = 0; nt < 4; ++nt) {
            f32x4 acc = {0.f, 0.f, 0.f, 0.f};
            acc = MFMA(alo, qh0[nt].h, acc);
            acc = MFMA(alo, qh0[nt].l, acc);
            acc = MFMA(ahi, qh1[nt].h, acc);
            acc = MFMA(ahi, qh1[nt].l, acc);
            const int qe = q0 + nt * 16 + lm;
            float ov[4];
#pragma unroll
            for (int r = 0; r < 4; ++r)
                ov[r] = (!diag || (kq + r <= qe)) ? acc[r] : 0.f;
            float4 o;
            o.x = ov[0]; o.y = ov[1]; o.z = ov[2]; o.w = ov[3];
            *reinterpret_cast<float4*>(&P[((size_t)bh * SQ + qe) * SK + kq]) = o;
        }
    }
    // zero-fill tiles fully above the diagonal
    const float4 z = {0.f, 0.f, 0.f, 0.f};
#pragma unroll 1
    for (int t = nt_; t < 16; ++t) {
        const int kq = t * 64 + w * 16 + lg * 4;
#pragma unroll
        for (int nt = 0; nt < 4; ++nt) {
            const int qe = q0 + nt * 16 + lm;
            *reinterpret_cast<float4*>(&P[((size_t)bh * SQ + qe) * SK + kq]) = z;
        }
    }
}

// ---------------- K2: rel+exp -> e to P, fused PR: out = (Σ e·bigr_v)/rowsum.
// Block per q (descending). e's MFMA C-layout (k=lg*4+r, bh=lm) is directly the
// A-fragment (m=lm, kk=lg*8+j) of the PR MFMA with kk=8*lg+j <-> k=4*lg+j
// (upper 4 kk slots of A and B zeroed -> half-K MFMA). rowsum recip -> rs[q][bh].
__global__ __launch_bounds__(256) void k_rel_pv(const float* __restrict__ query,
                                                const float* __restrict__ bigr_k,
                                                const float* __restrict__ bigr_v,
                                                float* __restrict__ P,
                                                float* __restrict__ out,
                                                float* __restrict__ rs) {
    __shared__ float4 buf[2][1024];  // staging; reused for pr cross-wave reduce
    __shared__ float red[4][64];
    __shared__ float rsum[64];
    const int q = SQ - 1 - (int)blockIdx.x;  // big rows first
    const int KE = q + 1;
    const int nt_ = (KE + 63) >> 6;
    const int tid = threadIdx.x;
    const int w = tid >> 6, l = tid & 63;
    const int lm = l & 15, lg = l >> 4;

    Frag2 qh0[4], qh1[4];  // pre-scaled
    float* prow[4];
#pragma unroll
    for (int nt = 0; nt < 4; ++nt) {
        const int bh = nt * 16 + lm;
        const float* qrow = query + ((size_t)bh * SQ + q) * DH + lg * 8;
        qh0[nt] = load_split(qrow, SCALE);
        qh1[nt] = load_split(qrow + 32, SCALE);
        prow[nt] = P + ((size_t)bh * SQ + q) * SK;
    }
    const float* bk = bigr_k + (size_t)q * SK * DH;
    const float* bv = bigr_v + (size_t)q * SK * DH;
    float lsum[4] = {0.f, 0.f, 0.f, 0.f};
    f32x4 pr[4][4];  // [nt(bh group)][ntd(d group)]
#pragma unroll
    for (int a = 0; a < 4; ++a)
#pragma unroll
        for (int b = 0; b < 4; ++b) pr[a][b] = (f32x4){0.f, 0.f, 0.f, 0.f};

    STAGE64(bk, 0);
#pragma unroll 1
    for (int t = 0; t < nt_; ++t) {
        const int kq = t * 64 + w * 16 + lg * 4;
        float4 pc[4];
#pragma unroll
        for (int nt = 0; nt < 4; ++nt)
            pc[nt] = *reinterpret_cast<const float4*>(prow[nt] + kq);
        // bigr_v B-fragments for this wave's 16-k stripe (consumed this iter)
        bf16x8 bvf[4];
        {
            const int kbw = t * 64 + w * 16 + 4 * lg;
#pragma unroll
            for (int ntd = 0; ntd < 4; ++ntd) {
                ushort8 u;
#pragma unroll
                for (int j = 0; j < 4; ++j)
                    u[j] = f2bf(bv[(size_t)(kbw + j) * DH + ntd * 16 + lm]);
                u[4] = 0; u[5] = 0; u[6] = 0; u[7] = 0;
                bvf[ntd] = __builtin_bit_cast(bf16x8, u);
            }
        }
        if (t + 1 < nt_) {
            STAGE64(bk + (size_t)(t + 1) * 64 * DH, (t + 1) & 1);
            WAITVN(4);  // stage(t)+pc+bv landed; stage(t+1) in flight
        } else {
            WAITVN(0);
        }
        const float4* L = buf[t & 1];
        const int R = w * 16 + lm;
        const int sw = R & 7;
        float4 f0 = L[R * 16 + ((2 * lg) ^ sw)];
        float4 f1 = L[R * 16 + ((2 * lg + 1) ^ sw)];
        float4 f2 = L[R * 16 + ((8 + 2 * lg) ^ sw)];
        float4 f3 = L[R * 16 + ((9 + 2 * lg) ^ sw)];
        bf16x8 alo = pack_bf8(f0, f1);
        bf16x8 ahi = pack_bf8(f2, f3);
#pragma unroll
        for (int nt = 0; nt < 4; ++nt) {
            f32x4 acc = {0.f, 0.f, 0.f, 0.f};
            acc = MFMA(alo, qh0[nt].h, acc);
            acc = MFMA(alo, qh0[nt].l, acc);
            acc = MFMA(ahi, qh1[nt].h, acc);
            acc = MFMA(ahi, qh1[nt].l, acc);
            const float4 c = pc[nt];
            float cv[4] = {c.x, c.y, c.z, c.w};
            float ov[4];
#pragma unroll
            for (int r = 0; r < 4; ++r) {
                float e = (kq + r < KE) ? __expf(cv[r] + acc[r]) : 0.f;
                ov[r] = e;
                lsum[nt] += e;
            }
            float4 o;
            o.x = ov[0]; o.y = ov[1]; o.z = ov[2]; o.w = ov[3];
            *reinterpret_cast<float4*>(prow[nt] + kq) = o;
            // PR accumulate: A = e (this lane's quad in slots 0..3), K=16 via
            // zeroed upper half; D[m=bh_in=lg*4+r][n=d_in=lm].
            ushort8 ua;
#pragma unroll
            for (int j = 0; j < 4; ++j) ua[j] = f2bf(ov[j]);
            ua[4] = 0; ua[5] = 0; ua[6] = 0; ua[7] = 0;
            bf16x8 af = __builtin_bit_cast(bf16x8, ua);
#pragma unroll
            for (int ntd = 0; ntd < 4; ++ntd)
                pr[nt][ntd] = MFMA(af, bvf[ntd], pr[nt][ntd]);
        }
    }

    // ---- row-sum reduce -> rsum (recip) in LDS + rs in global ----
#pragma unroll
    for (int nt = 0; nt < 4; ++nt) {
        float v = lsum[nt];
        v += __shfl_xor(v, 16);
        v += __shfl_xor(v, 32);
        if (l < 16) red[w][nt * 16 + l] = v;
    }
    __syncthreads();  // red ready; also: all staging reads of buf complete
    if (tid < 64) {
        float nr = 1.0f / (red[0][tid] + red[1][tid] + red[2][tid] + red[3][tid]);
        rsum[tid] = nr;
        rs[(size_t)q * 64 + tid] = nr;
    }
    // ---- pr cross-wave reduce in buf (32 KB = 2 halves of 4096 floats) ----
    float* prbuf = reinterpret_cast<float*>(&buf[0][0]);
    if (w < 2) {
        float* dst = prbuf + w * 4096;
#pragma unroll
        for (int nt = 0; nt < 4; ++nt)
#pragma unroll
            for (int ntd = 0; ntd < 4; ++ntd)
#pragma unroll
                for (int r = 0; r < 4; ++r)
                    dst[(nt * 16 + lg * 4 + r) * 64 + ntd * 16 + lm] = pr[nt][ntd][r];
    }
    __syncthreads();  // halves written (w0,w1); rsum ready
    if (w >= 2) {
        float* dst = prbuf + (w - 2) * 4096;
#pragma unroll
        for (int nt = 0; nt < 4; ++nt)
#pragma unroll
            for (int ntd = 0; ntd < 4; ++ntd)
#pragma unroll
                for (int r = 0; r < 4; ++r)
                    dst[(nt * 16 + lg * 4 + r) * 64 + ntd * 16 + lm] += pr[nt][ntd][r];
    }
    __syncthreads();
    // ---- final: out[bh][q][d] = (half0 + half1) * rsum[bh] ----
#pragma unroll
    for (int i = 0; i < 4; ++i) {
        const int f4i = tid + i * 256;  // 0..1023 float4s
        float4 a = reinterpret_cast<const float4*>(prbuf)[f4i];
        float4 b = reinterpret_cast<const float4*>(prbuf)[1024 + f4i];
        const int fl = f4i * 4;
        const int bh = fl >> 6, d = fl & 63;
        const float nr = rsum[bh];
        float4 o = {(a.x + b.x) * nr, (a.y + b.y) * nr,
                    (a.z + b.z) * nr, (a.w + b.w) * nr};
        *reinterpret_cast<float4*>(&out[((size_t)bh * SQ + q) * DH + d]) = o;
    }
}

// ---------------- K3: Pn = e*recip written in place (final p_attn);
// out += Pn @ V (unnormalized A, scaled by orecip at the end).
__global__ __launch_bounds__(256) void k_pv(float* __restrict__ P,
                                            const float* __restrict__ V,
                                            const float* __restrict__ rs,
                                            float* __restrict__ out) {
    const int qt = 15 - (int)blockIdx.x;  // big tiles first
    const int bh = blockIdx.y;
    const int tid = threadIdx.x;
    const int w = tid >> 6, l = tid & 63;
    const int lm = l & 15, lg = l >> 4;
    const int q0 = qt * 64 + w * 16;

    const float wrecip = rs[(size_t)(q0 + lm) * 64 + bh];
    float orecip[4];
#pragma unroll
    for (int r = 0; r < 4; ++r)
        orecip[r] = rs[(size_t)(q0 + lg * 4 + r) * 64 + bh];

    f32x4 acc[4] = {{0.f,0.f,0.f,0.f},{0.f,0.f,0.f,0.f},{0.f,0.f,0.f,0.f},{0.f,0.f,0.f,0.f}};
    const int kend = q0 + 16;
    for (int k0 = 0; k0 < kend; k0 += 32) {
        float* arow = P + ((size_t)bh * SQ + q0 + lm) * SK + k0 + lg * 8;
        float4 x0 = *reinterpret_cast<const float4*>(arow);
        float4 x1 = *reinterpret_cast<const float4*>(arow + 4);
        float4 y0 = {x0.x * wrecip, x0.y * wrecip, x0.z * wrecip, x0.w * wrecip};
        float4 y1 = {x1.x * wrecip, x1.y * wrecip, x1.z * wrecip, x1.w * wrecip};
        *reinterpret_cast<float4*>(arow) = y0;       // final normalized p_attn
        *reinterpret_cast<float4*>(arow + 4) = y1;
        bf16x8 a = pack_bf8(x0, x1);                 // unnormalized e
#pragma unroll
        for (int nt = 0; nt < 4; ++nt) {
            const float* bcol = V + ((size_t)bh * SK + k0 + lg * 8) * DH + nt * 16 + lm;
            bf16x8 b = load_bf8_strided(bcol, DH);
            acc[nt] = MFMA(a, b, acc[nt]);
        }
    }
#pragma unroll
    for (int nt = 0; nt < 4; ++nt)
#pragma unroll
        for (int r = 0; r < 4; ++r)
            out[((size_t)bh * SQ + q0 + lg * 4 + r) * DH + nt * 16 + lm] +=
                acc[nt][r] * orecip[r];
}

extern "C" void kernel_launch(void* const* d_in, const int* in_sizes, int n_in,
                              void* d_out, int out_size, void* d_ws, size_t ws_size,
                              hipStream_t stream) {
    const float* query  = (const float*)d_in[0];
    const float* key    = (const float*)d_in[1];
    const float* value  = (const float*)d_in[2];
    const float* bigr_k = (const float*)d_in[3];
    const float* bigr_v = (const float*)d_in[4];
    float* out = (float*)d_out;                       // BH*SQ*DH
    float* P   = out + (size_t)BH * SQ * DH;          // BH*SQ*SK
    float* rs  = (float*)d_ws;                        // [SQ][BH] recip = 256 KB

    k_scores<<<dim3(16, BH), 256, 0, stream>>>(query, key, P);
    k_rel_pv<<<dim3(SQ), 256, 0, stream>>>(query, bigr_k, bigr_v, P, out, rs);
    k_pv<<<dim3(16, BH), 256, 0, stream>>>(P, value, rs, out);
}

// Round 16
// 403.299 us; speedup vs baseline: 1.7870x; 1.1637x over previous
//
#include <hip/hip_runtime.h>
#include <hip/hip_bf16.h>

// Relative-position causal attention, B=4 H=16 Q=K=1024 D=64 (fp32 in/out).
// d_out = [output (BH*Q*D) | p_attn (BH*Q*K)] fp32.
// R15 inner code; this round changes ONLY block->work maps for CU balance:
//  k_scores/k_pv: 1-D grid, qt in HIGH bits (resident sets span sizes).
//  k_rel_pv: 4-stripe balanced q map (per-CU work sum constant).

#define BH 64
#define SQ 1024
#define SK 1024
#define DH 64
#define SCALE 0.125f

typedef __attribute__((ext_vector_type(4))) float f32x4;
typedef __attribute__((ext_vector_type(8))) unsigned short ushort8;
typedef __attribute__((ext_vector_type(8))) __bf16 bf16x8;

static __device__ inline unsigned short f2bf(float x) {
    unsigned u = __float_as_uint(x);
    unsigned r = u + 0x7FFFu + ((u >> 16) & 1u);
    return (unsigned short)(r >> 16);
}
static __device__ inline float bf2f(unsigned short s) {
    return __uint_as_float(((unsigned)s) << 16);
}

struct Frag2 { bf16x8 h, l; };

// Load 8 fp32, scale, split into hi/lo bf16 fragments (hi+lo == scaled value).
static __device__ inline Frag2 load_split(const float* __restrict__ p, float scale) {
    float4 x0 = *reinterpret_cast<const float4*>(p);
    float4 x1 = *reinterpret_cast<const float4*>(p + 4);
    float v[8] = {x0.x, x0.y, x0.z, x0.w, x1.x, x1.y, x1.z, x1.w};
    ushort8 uh, ul;
#pragma unroll
    for (int j = 0; j < 8; ++j) {
        float s = v[j] * scale;
        unsigned short h = f2bf(s);
        float r = s - bf2f(h);
        uh[j] = h;
        ul[j] = f2bf(r);
    }
    Frag2 f;
    f.h = __builtin_bit_cast(bf16x8, uh);
    f.l = __builtin_bit_cast(bf16x8, ul);
    return f;
}

static __device__ inline bf16x8 pack_bf8(float4 x0, float4 x1) {
    float v[8] = {x0.x, x0.y, x0.z, x0.w, x1.x, x1.y, x1.z, x1.w};
    ushort8 u;
#pragma unroll
    for (int j = 0; j < 8; ++j) u[j] = f2bf(v[j]);
    return __builtin_bit_cast(bf16x8, u);
}

static __device__ inline bf16x8 load_bf8(const float* __restrict__ p) {
    float4 x0 = *reinterpret_cast<const float4*>(p);
    float4 x1 = *reinterpret_cast<const float4*>(p + 4);
    return pack_bf8(x0, x1);
}

static __device__ inline bf16x8 load_bf8_strided(const float* __restrict__ p, int stride) {
    ushort8 u;
#pragma unroll
    for (int j = 0; j < 8; ++j) u[j] = f2bf(p[(size_t)j * stride]);
    return __builtin_bit_cast(bf16x8, u);
}

#define MFMA(a, b, c) __builtin_amdgcn_mfma_f32_16x16x32_bf16((a), (b), (c), 0, 0, 0)

// async global -> LDS, 16B per lane; lds dest is wave-uniform base + lane*16
#define GLLD(g, s)                                                              \
    __builtin_amdgcn_global_load_lds(                                           \
        (const __attribute__((address_space(1))) void*)(g),                     \
        (__attribute__((address_space(3))) void*)(s), 16, 0, 0)

// stage a 64x64 fp32 tile (rows at src0 + row*DH) into buf[b]; WAVE-PRIVATE:
// wave w stages rows [w*16, w*16+16) and later reads only those rows.
// source pre-swizzled (chunk ^= row&7) so linear LDS + swizzled reads match.
#define STAGE64(src0, b)                                                        \
    do {                                                                        \
        _Pragma("unroll")                                                       \
        for (int j_ = 0; j_ < 4; ++j_) {                                        \
            const int idx_ = w * 256 + j_ * 64 + l;                             \
            const int row_ = idx_ >> 4;                                         \
            const int g_ = (idx_ & 15) ^ (row_ & 7);                            \
            GLLD((src0) + (size_t)row_ * DH + g_ * 4,                           \
                 &buf[b][w * 256 + j_ * 64]);                                   \
        }                                                                       \
    } while (0)

#define WAITVN(n)                                                               \
    do {                                                                        \
        asm volatile("s_waitcnt vmcnt(" #n ")" ::: "memory");                   \
        __builtin_amdgcn_sched_barrier(0);                                      \
    } while (0)

// ---------------- K1: content scores Q@K^T * scale -> P (zeros above diag).
// 1-D grid: qt = bid>>6 (high bits), bh = bid&63 -> resident sets span sizes.
__global__ __launch_bounds__(256, 4) void k_scores(const float* __restrict__ qp,
                                                   const float* __restrict__ kp,
                                                   float* __restrict__ P) {
    __shared__ float4 buf[2][1024];
    const int bid = blockIdx.x;
    const int qt = bid >> 6;
    const int bh = bid & 63;
    const int tid = threadIdx.x;
    const int w = tid >> 6, l = tid & 63;
    const int lm = l & 15, lg = l >> 4;
    const int q0 = qt * 64;

    Frag2 qh0[4], qh1[4];  // pre-scaled by SCALE
#pragma unroll
    for (int nt = 0; nt < 4; ++nt) {
        const float* qrow = qp + ((size_t)bh * SQ + q0 + nt * 16 + lm) * DH + lg * 8;
        qh0[nt] = load_split(qrow, SCALE);
        qh1[nt] = load_split(qrow + 32, SCALE);
    }
    const float* kb = kp + (size_t)bh * SK * DH;
    const int nt_ = qt + 1;

    STAGE64(kb, 0);
#pragma unroll 1
    for (int t = 0; t < nt_; ++t) {
        if (t + 1 < nt_) {
            STAGE64(kb + (size_t)(t + 1) * 64 * DH, (t + 1) & 1);
            WAITVN(4);  // stage(t)+stores(t-1) landed; stage(t+1) in flight
        } else {
            WAITVN(0);
        }
        const float4* L = buf[t & 1];
        const int R = w * 16 + lm;
        const int sw = R & 7;
        float4 f0 = L[R * 16 + ((2 * lg) ^ sw)];
        float4 f1 = L[R * 16 + ((2 * lg + 1) ^ sw)];
        float4 f2 = L[R * 16 + ((8 + 2 * lg) ^ sw)];
        float4 f3 = L[R * 16 + ((9 + 2 * lg) ^ sw)];
        bf16x8 alo = pack_bf8(f0, f1);
        bf16x8 ahi = pack_bf8(f2, f3);
        const int kq = t * 64 + w * 16 + lg * 4;
        const bool diag = (t == qt);
#pragma unroll
        for (int nt = 0; nt < 4; ++nt) {
            f32x4 acc = {0.f, 0.f, 0.f, 0.f};
            acc = MFMA(alo, qh0[nt].h, acc);
            acc = MFMA(alo, qh0[nt].l, acc);
            acc = MFMA(ahi, qh1[nt].h, acc);
            acc = MFMA(ahi, qh1[nt].l, acc);
            const int qe = q0 + nt * 16 + lm;
            float ov[4];
#pragma unroll
            for (int r = 0; r < 4; ++r)
                ov[r] = (!diag || (kq + r <= qe)) ? acc[r] : 0.f;
            float4 o;
            o.x = ov[0]; o.y = ov[1]; o.z = ov[2]; o.w = ov[3];
            *reinterpret_cast<float4*>(&P[((size_t)bh * SQ + qe) * SK + kq]) = o;
        }
    }
    // zero-fill tiles fully above the diagonal
    const float4 z = {0.f, 0.f, 0.f, 0.f};
#pragma unroll 1
    for (int t = nt_; t < 16; ++t) {
        const int kq = t * 64 + w * 16 + lg * 4;
#pragma unroll
        for (int nt = 0; nt < 4; ++nt) {
            const int qe = q0 + nt * 16 + lm;
            *reinterpret_cast<float4*>(&P[((size_t)bh * SQ + qe) * SK + kq]) = z;
        }
    }
}

// ---------------- K2: rel+exp -> e to P, fused PR: out = (Σ e·bigr_v)/rowsum.
// 4-stripe balanced q map: per-CU resident work sum constant (round-robin).
__global__ __launch_bounds__(256) void k_rel_pv(const float* __restrict__ query,
                                                const float* __restrict__ bigr_k,
                                                const float* __restrict__ bigr_v,
                                                float* __restrict__ P,
                                                float* __restrict__ out,
                                                float* __restrict__ rs) {
    __shared__ float4 buf[2][1024];  // staging; reused for pr cross-wave reduce
    __shared__ float red[4][64];
    __shared__ float rsum[64];
    int q;
    {
        const int bid = blockIdx.x, c = bid & 255;
        switch (bid >> 8) {
            case 0:  q = 1023 - c; break;
            case 1:  q = c;        break;
            case 2:  q = 767 - c;  break;
            default: q = 256 + c;  break;
        }
    }
    const int KE = q + 1;
    const int nt_ = (KE + 63) >> 6;
    const int tid = threadIdx.x;
    const int w = tid >> 6, l = tid & 63;
    const int lm = l & 15, lg = l >> 4;

    Frag2 qh0[4], qh1[4];  // pre-scaled
    float* prow[4];
#pragma unroll
    for (int nt = 0; nt < 4; ++nt) {
        const int bh = nt * 16 + lm;
        const float* qrow = query + ((size_t)bh * SQ + q) * DH + lg * 8;
        qh0[nt] = load_split(qrow, SCALE);
        qh1[nt] = load_split(qrow + 32, SCALE);
        prow[nt] = P + ((size_t)bh * SQ + q) * SK;
    }
    const float* bk = bigr_k + (size_t)q * SK * DH;
    const float* bv = bigr_v + (size_t)q * SK * DH;
    float lsum[4] = {0.f, 0.f, 0.f, 0.f};
    f32x4 pr[4][4];  // [nt(bh group)][ntd(d group)]
#pragma unroll
    for (int a = 0; a < 4; ++a)
#pragma unroll
        for (int b = 0; b < 4; ++b) pr[a][b] = (f32x4){0.f, 0.f, 0.f, 0.f};

    STAGE64(bk, 0);
#pragma unroll 1
    for (int t = 0; t < nt_; ++t) {
        const int kq = t * 64 + w * 16 + lg * 4;
        float4 pc[4];
#pragma unroll
        for (int nt = 0; nt < 4; ++nt)
            pc[nt] = *reinterpret_cast<const float4*>(prow[nt] + kq);
        // bigr_v B-fragments for this wave's 16-k stripe (consumed this iter)
        bf16x8 bvf[4];
        {
            const int kbw = t * 64 + w * 16 + 4 * lg;
#pragma unroll
            for (int ntd = 0; ntd < 4; ++ntd) {
                ushort8 u;
#pragma unroll
                for (int j = 0; j < 4; ++j)
                    u[j] = f2bf(bv[(size_t)(kbw + j) * DH + ntd * 16 + lm]);
                u[4] = 0; u[5] = 0; u[6] = 0; u[7] = 0;
                bvf[ntd] = __builtin_bit_cast(bf16x8, u);
            }
        }
        if (t + 1 < nt_) {
            STAGE64(bk + (size_t)(t + 1) * 64 * DH, (t + 1) & 1);
            WAITVN(4);  // stage(t)+pc+bv landed; stage(t+1) in flight
        } else {
            WAITVN(0);
        }
        const float4* L = buf[t & 1];
        const int R = w * 16 + lm;
        const int sw = R & 7;
        float4 f0 = L[R * 16 + ((2 * lg) ^ sw)];
        float4 f1 = L[R * 16 + ((2 * lg + 1) ^ sw)];
        float4 f2 = L[R * 16 + ((8 + 2 * lg) ^ sw)];
        float4 f3 = L[R * 16 + ((9 + 2 * lg) ^ sw)];
        bf16x8 alo = pack_bf8(f0, f1);
        bf16x8 ahi = pack_bf8(f2, f3);
#pragma unroll
        for (int nt = 0; nt < 4; ++nt) {
            f32x4 acc = {0.f, 0.f, 0.f, 0.f};
            acc = MFMA(alo, qh0[nt].h, acc);
            acc = MFMA(alo, qh0[nt].l, acc);
            acc = MFMA(ahi, qh1[nt].h, acc);
            acc = MFMA(ahi, qh1[nt].l, acc);
            const float4 c = pc[nt];
            float cv[4] = {c.x, c.y, c.z, c.w};
            float ov[4];
#pragma unroll
            for (int r = 0; r < 4; ++r) {
                float e = (kq + r < KE) ? __expf(cv[r] + acc[r]) : 0.f;
                ov[r] = e;
                lsum[nt] += e;
            }
            float4 o;
            o.x = ov[0]; o.y = ov[1]; o.z = ov[2]; o.w = ov[3];
            *reinterpret_cast<float4*>(prow[nt] + kq) = o;
            // PR accumulate: A = e (this lane's quad in slots 0..3), K=16 via
            // zeroed upper half; D[m=bh_in=lg*4+r][n=d_in=lm].
            ushort8 ua;
#pragma unroll
            for (int j = 0; j < 4; ++j) ua[j] = f2bf(ov[j]);
            ua[4] = 0; ua[5] = 0; ua[6] = 0; ua[7] = 0;
            bf16x8 af = __builtin_bit_cast(bf16x8, ua);
#pragma unroll
            for (int ntd = 0; ntd < 4; ++ntd)
                pr[nt][ntd] = MFMA(af, bvf[ntd], pr[nt][ntd]);
        }
    }

    // ---- row-sum reduce -> rsum (recip) in LDS + rs in global ----
#pragma unroll
    for (int nt = 0; nt < 4; ++nt) {
        float v = lsum[nt];
        v += __shfl_xor(v, 16);
        v += __shfl_xor(v, 32);
        if (l < 16) red[w][nt * 16 + l] = v;
    }
    __syncthreads();  // red ready; also: all staging reads of buf complete
    if (tid < 64) {
        float nr = 1.0f / (red[0][tid] + red[1][tid] + red[2][tid] + red[3][tid]);
        rsum[tid] = nr;
        rs[(size_t)q * 64 + tid] = nr;
    }
    // ---- pr cross-wave reduce in buf (32 KB = 2 halves of 4096 floats) ----
    float* prbuf = reinterpret_cast<float*>(&buf[0][0]);
    if (w < 2) {
        float* dst = prbuf + w * 4096;
#pragma unroll
        for (int nt = 0; nt < 4; ++nt)
#pragma unroll
            for (int ntd = 0; ntd < 4; ++ntd)
#pragma unroll
                for (int r = 0; r < 4; ++r)
                    dst[(nt * 16 + lg * 4 + r) * 64 + ntd * 16 + lm] = pr[nt][ntd][r];
    }
    __syncthreads();  // halves written (w0,w1); rsum ready
    if (w >= 2) {
        float* dst = prbuf + (w - 2) * 4096;
#pragma unroll
        for (int nt = 0; nt < 4; ++nt)
#pragma unroll
            for (int ntd = 0; ntd < 4; ++ntd)
#pragma unroll
                for (int r = 0; r < 4; ++r)
                    dst[(nt * 16 + lg * 4 + r) * 64 + ntd * 16 + lm] += pr[nt][ntd][r];
    }
    __syncthreads();
    // ---- final: out[bh][q][d] = (half0 + half1) * rsum[bh] ----
#pragma unroll
    for (int i = 0; i < 4; ++i) {
        const int f4i = tid + i * 256;  // 0..1023 float4s
        float4 a = reinterpret_cast<const float4*>(prbuf)[f4i];
        float4 b = reinterpret_cast<const float4*>(prbuf)[1024 + f4i];
        const int fl = f4i * 4;
        const int bh = fl >> 6, d = fl & 63;
        const float nr = rsum[bh];
        float4 o = {(a.x + b.x) * nr, (a.y + b.y) * nr,
                    (a.z + b.z) * nr, (a.w + b.w) * nr};
        *reinterpret_cast<float4*>(&out[((size_t)bh * SQ + q) * DH + d]) = o;
    }
}

// ---------------- K3: Pn = e*recip written in place (final p_attn);
// out += Pn @ V. 1-D grid: qt = bid>>6, bh = bid&63 (balanced residency).
__global__ __launch_bounds__(256) void k_pv(float* __restrict__ P,
                                            const float* __restrict__ V,
                                            const float* __restrict__ rs,
                                            float* __restrict__ out) {
    const int bid = blockIdx.x;
    const int qt = bid >> 6;
    const int bh = bid & 63;
    const int tid = threadIdx.x;
    const int w = tid >> 6, l = tid & 63;
    const int lm = l & 15, lg = l >> 4;
    const int q0 = qt * 64 + w * 16;

    const float wrecip = rs[(size_t)(q0 + lm) * 64 + bh];
    float orecip[4];
#pragma unroll
    for (int r = 0; r < 4; ++r)
        orecip[r] = rs[(size_t)(q0 + lg * 4 + r) * 64 + bh];

    f32x4 acc[4] = {{0.f,0.f,0.f,0.f},{0.f,0.f,0.f,0.f},{0.f,0.f,0.f,0.f},{0.f,0.f,0.f,0.f}};
    const int kend = q0 + 16;
    for (int k0 = 0; k0 < kend; k0 += 32) {
        float* arow = P + ((size_t)bh * SQ + q0 + lm) * SK + k0 + lg * 8;
        float4 x0 = *reinterpret_cast<const float4*>(arow);
        float4 x1 = *reinterpret_cast<const float4*>(arow + 4);
        float4 y0 = {x0.x * wrecip, x0.y * wrecip, x0.z * wrecip, x0.w * wrecip};
        float4 y1 = {x1.x * wrecip, x1.y * wrecip, x1.z * wrecip, x1.w * wrecip};
        *reinterpret_cast<float4*>(arow) = y0;       // final normalized p_attn
        *reinterpret_cast<float4*>(arow + 4) = y1;
        bf16x8 a = pack_bf8(x0, x1);                 // unnormalized e
#pragma unroll
        for (int nt = 0; nt < 4; ++nt) {
            const float* bcol = V + ((size_t)bh * SK + k0 + lg * 8) * DH + nt * 16 + lm;
            bf16x8 b = load_bf8_strided(bcol, DH);
            acc[nt] = MFMA(a, b, acc[nt]);
        }
    }
#pragma unroll
    for (int nt = 0; nt < 4; ++nt)
#pragma unroll
        for (int r = 0; r < 4; ++r)
            out[((size_t)bh * SQ + q0 + lg * 4 + r) * DH + nt * 16 + lm] +=
                acc[nt][r] * orecip[r];
}

extern "C" void kernel_launch(void* const* d_in, const int* in_sizes, int n_in,
                              void* d_out, int out_size, void* d_ws, size_t ws_size,
                              hipStream_t stream) {
    const float* query  = (const float*)d_in[0];
    const float* key    = (const float*)d_in[1];
    const float* value  = (const float*)d_in[2];
    const float* bigr_k = (const float*)d_in[3];
    const float* bigr_v = (const float*)d_in[4];
    float* out = (float*)d_out;                       // BH*SQ*DH
    float* P   = out + (size_t)BH * SQ * DH;          // BH*SQ*SK
    float* rs  = (float*)d_ws;                        // [SQ][BH] recip = 256 KB

    k_scores<<<dim3(1024), 256, 0, stream>>>(query, key, P);
    k_rel_pv<<<dim3(SQ), 256, 0, stream>>>(query, bigr_k, bigr_v, P, out, rs);
    k_pv<<<dim3(1024), 256, 0, stream>>>(P, value, rs, out);
}